// Round 2
// baseline (577.120 us; speedup 1.0000x reference)
//
#include <hip/hip_runtime.h>
#include <stdint.h>

#define NN 8192
#define DIM 128
#define ALPHA 0.2f
#define NK (NN / 32)          // 256 K-steps of 32
#define PF 4                  // prefetch depth (K-steps)

typedef float f32x4 __attribute__((ext_vector_type(4)));
typedef short bf16x8 __attribute__((ext_vector_type(8)));

__device__ __forceinline__ float b2f(uint32_t u){
  uint32_t x = u << 16;
  float f;
  __builtin_memcpy(&f, &x, 4);
  return f;
}
__device__ __forceinline__ uint16_t f2b(float f){
  uint32_t x;
  __builtin_memcpy(&x, &f, 4);
  x += 0x7FFFu + ((x >> 16) & 1u);
  return (uint16_t)(x >> 16);
}

// s1[i] = nodes[i,:] . a[0:128], s2[i] = nodes[i,:] . a[128:256]  (all fp32)
__global__ void s_kernel(const float* __restrict__ nodes,
                         const float* __restrict__ a,
                         float* __restrict__ s1, float* __restrict__ s2){
  int row  = blockIdx.x * 4 + (threadIdx.x >> 6);
  int lane = threadIdx.x & 63;
  float2 nv  = *(const float2*)(nodes + row * DIM + lane * 2);
  float2 a1v = *(const float2*)(a + lane * 2);
  float2 a2v = *(const float2*)(a + DIM + lane * 2);
  float p1 = nv.x * a1v.x + nv.y * a1v.y;
  float p2 = nv.x * a2v.x + nv.y * a2v.y;
  #pragma unroll
  for (int off = 32; off; off >>= 1){
    p1 += __shfl_down(p1, off);
    p2 += __shfl_down(p2, off);
  }
  if (lane == 0){ s1[row] = p1; s2[row] = p2; }
}

// nodesT[n][k] = bf16(nodes[k][n])
__global__ void t_kernel(const float* __restrict__ nodes,
                         uint16_t* __restrict__ nodesT){
  __shared__ uint16_t tile[32][33];
  int kb = blockIdx.x * 32, nb = blockIdx.y * 32;
  int tx = threadIdx.x & 31, ty = threadIdx.x >> 5;
  for (int r = ty; r < 32; r += 8)
    tile[r][tx] = f2b(nodes[(size_t)(kb + r) * DIM + nb + tx]);
  __syncthreads();
  for (int r = ty; r < 32; r += 8)
    nodesT[(size_t)(nb + r) * NN + kb + tx] = tile[tx][r];
}

// Barrier-free GAT row-block: ONE wave owns 16 rows x 128 dims.
// Lane (c = lane&15, g = lane>>4) computes W[i0+c][k] for k = kk*32+g*8..+8
// directly in the MFMA A-fragment layout from a register-pipelined dist
// stream; 8 MFMAs (one per 16-dim tile) per K=32 step. No LDS, no barriers.
__global__ void __launch_bounds__(64)
attn_kernel(const float* __restrict__ dist,
            const uint16_t* __restrict__ nodesT,
            const float* __restrict__ s1,
            const float* __restrict__ s2,
            float* __restrict__ out){
  const int lane = threadIdx.x;
  const int c    = lane & 15;
  const int g    = lane >> 4;
  const int i0   = blockIdx.x * 16;

  const float  s1v  = s1[i0 + c];
  const float* dptr = dist + (size_t)(i0 + c) * NN + g * 8;
  const float* sptr = s2 + g * 8;

  f32x4 acc[8];
  #pragma unroll
  for (int d = 0; d < 8; d++) acc[d] = (f32x4){0.f, 0.f, 0.f, 0.f};
  float den = 0.f;

  // register prefetch pipeline, statically indexed (rule #20)
  float4 pd0[PF], pd1[PF], ps0[PF], ps1[PF];
  #pragma unroll
  for (int p = 0; p < PF; p++){
    pd0[p] = *(const float4*)(dptr + p * 32);
    pd1[p] = *(const float4*)(dptr + p * 32 + 4);
    ps0[p] = *(const float4*)(sptr + p * 32);
    ps1[p] = *(const float4*)(sptr + p * 32 + 4);
  }

  auto stage = [&](int p, int kk, bool prefetch){
    // B fragments for this K-step (L2-resident nodesT)
    bf16x8 bv[8];
    #pragma unroll
    for (int d = 0; d < 8; d++)
      bv[d] = *(const bf16x8*)(nodesT + (size_t)(d * 16 + c) * NN + kk * 32 + g * 8);

    // W for this lane's 8 k's, from pipeline stage p
    float dv[8] = {pd0[p].x, pd0[p].y, pd0[p].z, pd0[p].w,
                   pd1[p].x, pd1[p].y, pd1[p].z, pd1[p].w};
    float sv[8] = {ps0[p].x, ps0[p].y, ps0[p].z, ps0[p].w,
                   ps1[p].x, ps1[p].y, ps1[p].z, ps1[p].w};
    union { bf16x8 v; uint16_t u[8]; } w;
    #pragma unroll
    for (int j = 0; j < 8; j++){
      float x = s1v + sv[j];
      float e = fmaxf(x, ALPHA * x);
      float wf = (dv[j] < 0.5f) ? __expf(e) : 0.f;
      uint16_t wq = f2b(wf);
      w.u[j] = wq;
      den += b2f((uint32_t)wq);     // denominator sees the SAME quantized W
    }

    // refill stage p with kk+PF (issues early; consumed PF steps later)
    if (prefetch){
      const int kn = kk + PF;
      pd0[p] = *(const float4*)(dptr + kn * 32);
      pd1[p] = *(const float4*)(dptr + kn * 32 + 4);
      ps0[p] = *(const float4*)(sptr + kn * 32);
      ps1[p] = *(const float4*)(sptr + kn * 32 + 4);
    }

    #pragma unroll
    for (int d = 0; d < 8; d++)
      acc[d] = __builtin_amdgcn_mfma_f32_16x16x32_bf16(w.v, bv[d], acc[d], 0, 0, 0);
  };

  // main loop: unconditional prefetch
  for (int kko = 0; kko < NK - PF; kko += PF){
    #pragma unroll
    for (int p = 0; p < PF; p++)
      stage(p, kko + p, true);
  }
  // epilogue: drain the last PF stages, no prefetch
  #pragma unroll
  for (int p = 0; p < PF; p++)
    stage(p, NK - PF + p, false);

  // ---- denominator: row c's partials live in lanes c, c+16, c+32, c+48 ----
  den += __shfl_down(den, 32);
  den += __shfl_down(den, 16);
  // lanes 0..15 now hold full row denominators

  float inv[4];
  #pragma unroll
  for (int r = 0; r < 4; r++)
    inv[r] = 1.0f / __shfl(den, g * 4 + r);

  // ---- store: D layout col=c, row=g*4+r (verified mapping) ----
  #pragma unroll
  for (int d = 0; d < 8; d++)
    #pragma unroll
    for (int r = 0; r < 4; r++)
      out[(size_t)(i0 + g * 4 + r) * DIM + d * 16 + c] = acc[d][r] * inv[r];
}

extern "C" void kernel_launch(void* const* d_in, const int* in_sizes, int n_in,
                              void* d_out, int out_size, void* d_ws, size_t ws_size,
                              hipStream_t stream){
  const float* nodes = (const float*)d_in[0];
  const float* dist  = (const float*)d_in[1];
  const float* a     = (const float*)d_in[2];
  float* out = (float*)d_out;

  char* ws = (char*)d_ws;
  float*    s1     = (float*)ws;                     // 32 KB
  float*    s2     = (float*)(ws + (32 << 10));      // 32 KB
  uint16_t* nodesT = (uint16_t*)(ws + (64 << 10));   // 2 MB

  s_kernel<<<NN / 4, 256, 0, stream>>>(nodes, a, s1, s2);
  t_kernel<<<dim3(NN / 32, DIM / 32), 256, 0, stream>>>(nodes, nodesT);
  attn_kernel<<<NN / 16, 64, 0, stream>>>(dist, nodesT, s1, s2, out);
}

// Round 3
// 397.638 us; speedup vs baseline: 1.4514x; 1.4514x over previous
//
#include <hip/hip_runtime.h>
#include <stdint.h>

#define NN 8192
#define DIM 128
#define ALPHA 0.2f
#define MTILE 32
#define BTHREADS 512          // 8 waves = 4 n-quarters x 2 k-halves
#define BK 256                // k-chunk per LDS tile
#define NCHUNK (NN / BK)      // 32
#define WSTRIDE (BK + 8)      // pad: row stride 132 words -> conflict-free b128 r/w

typedef float f32x16 __attribute__((ext_vector_type(16)));
typedef short bf16x8 __attribute__((ext_vector_type(8)));

__device__ __forceinline__ float b2f(uint32_t u){
  uint32_t x = u << 16;
  float f;
  __builtin_memcpy(&f, &x, 4);
  return f;
}
__device__ __forceinline__ uint16_t f2b(float f){
  uint32_t x;
  __builtin_memcpy(&x, &f, 4);
  x += 0x7FFFu + ((x >> 16) & 1u);
  return (uint16_t)(x >> 16);
}

// Raw workgroup barrier: flush LDS ops (lgkm) but DO NOT drain vmcnt —
// staged global loads stay in flight across it (T3/T4, m201-verified).
__device__ __forceinline__ void bar_lds(){
  asm volatile("s_waitcnt lgkmcnt(0)" ::: "memory");
  __builtin_amdgcn_s_barrier();
  asm volatile("" ::: "memory");
}

// s1[i] = nodes[i,:] . a[0:128], s2[i] = nodes[i,:] . a[128:256]  (all fp32)
__global__ void s_kernel(const float* __restrict__ nodes,
                         const float* __restrict__ a,
                         float* __restrict__ s1, float* __restrict__ s2){
  int row  = blockIdx.x * 4 + (threadIdx.x >> 6);
  int lane = threadIdx.x & 63;
  float2 nv  = *(const float2*)(nodes + row * DIM + lane * 2);
  float2 a1v = *(const float2*)(a + lane * 2);
  float2 a2v = *(const float2*)(a + DIM + lane * 2);
  float p1 = nv.x * a1v.x + nv.y * a1v.y;
  float p2 = nv.x * a2v.x + nv.y * a2v.y;
  #pragma unroll
  for (int off = 32; off; off >>= 1){
    p1 += __shfl_down(p1, off);
    p2 += __shfl_down(p2, off);
  }
  if (lane == 0){ s1[row] = p1; s2[row] = p2; }
}

// nodesT[n][k] = bf16(nodes[k][n])
__global__ void t_kernel(const float* __restrict__ nodes,
                         uint16_t* __restrict__ nodesT){
  __shared__ uint16_t tile[32][33];
  int kb = blockIdx.x * 32, nb = blockIdx.y * 32;
  int tx = threadIdx.x & 31, ty = threadIdx.x >> 5;
  for (int r = ty; r < 32; r += 8)
    tile[r][tx] = f2b(nodes[(size_t)(kb + r) * DIM + nb + tx]);
  __syncthreads();
  for (int r = ty; r < 32; r += 8)
    nodesT[(size_t)(nb + r) * NN + kb + tx] = tile[tx][r];
}

// Fused GAT row-block, round-0 structure + 2-deep cross-barrier pipeline.
__global__ void __launch_bounds__(BTHREADS)
attn_kernel(const float* __restrict__ dist,
            const uint16_t* __restrict__ nodesT,
            const float* __restrict__ s1,
            const float* __restrict__ s2,
            float* __restrict__ out){
  __shared__ uint16_t Wbuf[2][MTILE][WSTRIDE];   // 33.8 KB
  __shared__ float accT[MTILE][DIM];             // 16 KB
  __shared__ float denT[MTILE];

  const int tid  = threadIdx.x;
  const int lane = tid & 63;
  const int wave = tid >> 6;
  const int i0   = blockIdx.x * MTILE;

  // ---- W-gen mapping: thread -> (row, 16 k's split as wr*8 + {0,128}) ----
  const int wrow = tid >> 4;          // 0..31
  const int wr   = tid & 15;          // 0..15
  const float s1v = s1[i0 + wrow];
  const float* distRow = dist + (size_t)(i0 + wrow) * NN + wr * 8;

  // ---- MFMA mapping: wave -> (n-quarter q, k-half h) ----
  const int q    = wave & 3;
  const int h    = wave >> 2;
  const int m    = lane & 31;
  const int half = lane >> 5;
  const uint16_t* bRow = nodesT + (size_t)(q * 32 + m) * NN;

  f32x16 acc;
  #pragma unroll
  for (int i = 0; i < 16; i++) acc[i] = 0.f;
  float den = 0.f;

  // two statically-named register staging sets (rule #20)
  float4 Ad0, Ad1, Ad2, Ad3, As0, As1, As2, As3;
  float4 Bd0, Bd1, Bd2, Bd3, Bs0, Bs1, Bs2, Bs3;

#define LOADC(d0,d1,d2,d3,e0,e1,e2,e3, s_) do{                         \
    const float* dpp = distRow + (size_t)(s_) * BK;                    \
    const float* spp = s2 + (s_) * BK + wr * 8;                        \
    d0 = *(const float4*)(dpp);        d1 = *(const float4*)(dpp + 4); \
    d2 = *(const float4*)(dpp + 128);  d3 = *(const float4*)(dpp + 132);\
    e0 = *(const float4*)(spp);        e1 = *(const float4*)(spp + 4); \
    e2 = *(const float4*)(spp + 128);  e3 = *(const float4*)(spp + 132);\
  }while(0)

#define GENW(d0,d1,d2,d3,e0,e1,e2,e3, buf_) do{                        \
    float dv[16] = {d0.x,d0.y,d0.z,d0.w, d1.x,d1.y,d1.z,d1.w,          \
                    d2.x,d2.y,d2.z,d2.w, d3.x,d3.y,d3.z,d3.w};         \
    float sv[16] = {e0.x,e0.y,e0.z,e0.w, e1.x,e1.y,e1.z,e1.w,          \
                    e2.x,e2.y,e2.z,e2.w, e3.x,e3.y,e3.z,e3.w};         \
    union { bf16x8 v; uint16_t u[8]; } w0, w1;                         \
    _Pragma("unroll")                                                  \
    for (int j = 0; j < 8; j++){                                       \
      float x = s1v + sv[j];                                           \
      float e = fmaxf(x, ALPHA * x);                                   \
      float w = (dv[j] < 0.5f) ? __expf(e) : 0.f;                      \
      uint16_t wq = f2b(w);                                            \
      w0.u[j] = wq;                                                    \
      den += b2f((uint32_t)wq);                                        \
    }                                                                  \
    _Pragma("unroll")                                                  \
    for (int j = 0; j < 8; j++){                                       \
      float x = s1v + sv[8 + j];                                       \
      float e = fmaxf(x, ALPHA * x);                                   \
      float w = (dv[8 + j] < 0.5f) ? __expf(e) : 0.f;                  \
      uint16_t wq = f2b(w);                                            \
      w1.u[j] = wq;                                                    \
      den += b2f((uint32_t)wq);                                        \
    }                                                                  \
    *(bf16x8*)&Wbuf[buf_][wrow][wr * 8]       = w0.v;                  \
    *(bf16x8*)&Wbuf[buf_][wrow][wr * 8 + 128] = w1.v;                  \
  }while(0)

#define MFMAC(buf_, s_) do{                                            \
    const size_t kb = (size_t)(s_) * BK;                               \
    bf16x8 bvv[8];                                                     \
    _Pragma("unroll")                                                  \
    for (int kk = 0; kk < 8; kk++)                                     \
      bvv[kk] = *(const bf16x8*)(bRow + kb + h * 128 + kk * 16 + half * 8);\
    _Pragma("unroll")                                                  \
    for (int kk = 0; kk < 8; kk++){                                    \
      int ko = h * 128 + kk * 16 + half * 8;                           \
      bf16x8 av = *(const bf16x8*)&Wbuf[buf_][m][ko];                  \
      acc = __builtin_amdgcn_mfma_f32_32x32x16_bf16(av, bvv[kk], acc, 0, 0, 0);\
    }                                                                  \
  }while(0)

  // Prologue: chunk 0 -> buf0 (serial, once); chunk 1 in flight in B.
  LOADC(Ad0,Ad1,Ad2,Ad3,As0,As1,As2,As3, 0);
  GENW (Ad0,Ad1,Ad2,Ad3,As0,As1,As2,As3, 0);
  LOADC(Bd0,Bd1,Bd2,Bd3,Bs0,Bs1,Bs2,Bs3, 1);

  for (int s = 0; s < NCHUNK; s += 2){
    bar_lds();                                   // buf0 (chunk s) ready
    if (s + 2 < NCHUNK)
      LOADC(Ad0,Ad1,Ad2,Ad3,As0,As1,As2,As3, s + 2);
    MFMAC(0, s);
    GENW (Bd0,Bd1,Bd2,Bd3,Bs0,Bs1,Bs2,Bs3, 1);  // chunk s+1 -> buf1

    bar_lds();                                   // buf1 (chunk s+1) ready
    if (s + 3 < NCHUNK)
      LOADC(Bd0,Bd1,Bd2,Bd3,Bs0,Bs1,Bs2,Bs3, s + 3);
    MFMAC(1, s + 1);
    if (s + 2 < NCHUNK)
      GENW (Ad0,Ad1,Ad2,Ad3,As0,As1,As2,As3, 0); // chunk s+2 -> buf0
  }

  // ---- denominator: 16 threads per row, all in one wave -> shfl reduce ----
  den += __shfl_down(den, 8, 16);
  den += __shfl_down(den, 4, 16);
  den += __shfl_down(den, 2, 16);
  den += __shfl_down(den, 1, 16);
  if (wr == 0) denT[wrow] = 1.0f / den;

  // ---- combine k-half pairs via LDS, normalize, store fp32 ----
  if (h == 0){
    #pragma unroll
    for (int r = 0; r < 16; r++){
      int row = (r & 3) + 8 * (r >> 2) + 4 * half;
      accT[row][q * 32 + m] = acc[r];
    }
  }
  __syncthreads();
  if (h == 1){
    #pragma unroll
    for (int r = 0; r < 16; r++){
      int row = (r & 3) + 8 * (r >> 2) + 4 * half;
      float v = (accT[row][q * 32 + m] + acc[r]) * denT[row];
      out[(size_t)(i0 + row) * DIM + q * 32 + m] = v;
    }
  }
}

extern "C" void kernel_launch(void* const* d_in, const int* in_sizes, int n_in,
                              void* d_out, int out_size, void* d_ws, size_t ws_size,
                              hipStream_t stream){
  const float* nodes = (const float*)d_in[0];
  const float* dist  = (const float*)d_in[1];
  const float* a     = (const float*)d_in[2];
  float* out = (float*)d_out;

  char* ws = (char*)d_ws;
  float*    s1     = (float*)ws;                     // 32 KB
  float*    s2     = (float*)(ws + (32 << 10));      // 32 KB
  uint16_t* nodesT = (uint16_t*)(ws + (64 << 10));   // 2 MB

  s_kernel<<<NN / 4, 256, 0, stream>>>(nodes, a, s1, s2);
  t_kernel<<<dim3(NN / 32, DIM / 32), 256, 0, stream>>>(nodes, nodesT);
  attn_kernel<<<NN / MTILE, BTHREADS, 0, stream>>>(dist, nodesT, s1, s2, out);
}